// Round 3
// baseline (1030.088 us; speedup 1.0000x reference)
//
#include <hip/hip_runtime.h>
#include <cstdint>
#include <cstddef>

typedef short short8 __attribute__((ext_vector_type(8)));
typedef float floatx4 __attribute__((ext_vector_type(4)));
typedef unsigned short u16;

__device__ __forceinline__ u16 f2bf(float f) {
    unsigned u = __float_as_uint(f);
    u += 0x7FFFu + ((u >> 16) & 1u);
    return (u16)(u >> 16);
}
__device__ __forceinline__ float bf2f(u16 h) {
    return __uint_as_float(((unsigned)h) << 16);
}

// ---------------------------------------------------------------------------
// Kernel 1: x [4][72][32][32][32] f32 (NCDHW)  ->  xt [4][32][32][32][72] bf16
// ---------------------------------------------------------------------------
__global__ __launch_bounds__(256) void k_transpose_x(const float* __restrict__ x,
                                                     u16* __restrict__ xt) {
    __shared__ float tile[72 * 33];
    const int bx = blockIdx.x;               // ((b*32+d)*32+h)
    const int tid = threadIdx.x;
    const int b = bx >> 10, d = (bx >> 5) & 31, h = bx & 31;
    const float* src = x + (size_t)b * 72 * 32768 + d * 1024 + h * 32;
    for (int e = tid; e < 2304; e += 256) {
        int ci = e >> 5, w = e & 31;
        tile[ci * 33 + w] = src[(size_t)ci * 32768 + w];
    }
    __syncthreads();
    u16* dst = xt + (size_t)bx * 2304;
    for (int e = tid; e < 2304; e += 256) {
        int w = e / 72, ci = e - w * 72;
        dst[e] = f2bf(tile[ci * 33 + w]);
    }
}

// ---------------------------------------------------------------------------
// Kernel 2: W [176][72][5][5][5] f32 -> wt bf16 per-lane B-fragment layout:
//   wt[kd][kh][kblk(12)][nblk(11)][lane(64)][8]
// ---------------------------------------------------------------------------
__global__ __launch_bounds__(256) void k_prep_w(const float* __restrict__ W,
                                                u16* __restrict__ wt) {
    const int gid = blockIdx.x * 256 + threadIdx.x;   // 825*256 = 211200 = 3300 frags * 64
    const int frag = gid >> 6, lane = gid & 63;
    const int nb = frag % 11;
    int t = frag / 11;
    const int kb = t % 12;
    t = t / 12;
    const int kh = t % 5, kd = t / 5;
    const int n = lane & 15, q8 = (lane >> 4) * 8;
    const int co = nb * 16 + n;
    u16 v[8] __attribute__((aligned(16)));
    #pragma unroll
    for (int j = 0; j < 8; ++j) {
        int k = kb * 32 + q8 + j;
        u16 r = 0;
        if (k < 360) {
            int kw = k / 72, ci = k - kw * 72;
            r = f2bf(W[((size_t)co * 72 + ci) * 125 + kd * 25 + kh * 5 + kw]);
        }
        v[j] = r;
    }
    *(uint4*)(wt + (size_t)gid * 8) = *(const uint4*)v;
}

// ---------------------------------------------------------------------------
// Kernel 3: implicit-GEMM conv + fused gating.
// Register-lean inner loop: depth-2 rotating B queue, schedule pinned with
// sched_group_barrier (1 VMEM_READ + 4 MFMA per group) so the compiler cannot
// hoist all 11 B loads (which costs ~88 VGPRs and caps occupancy at 6 waves/CU).
// Target: total regs <= 256 -> 8 waves/CU (2/SIMD).
// ---------------------------------------------------------------------------
#define LP 2624

#define GRP(kb_, nb_) do {                                                             \
    short8 bv = q[((kb_) + (nb_)) & 1];                                                \
    q[((kb_) + (nb_)) & 1] = *(const short8*)(bq + (size_t)((kb_) * 11 + (nb_) + 2) * 512); \
    acc[0][(nb_)] = __builtin_amdgcn_mfma_f32_16x16x32_bf16(A0, bv, acc[0][(nb_)], 0, 0, 0); \
    acc[1][(nb_)] = __builtin_amdgcn_mfma_f32_16x16x32_bf16(A1, bv, acc[1][(nb_)], 0, 0, 0); \
    acc[2][(nb_)] = __builtin_amdgcn_mfma_f32_16x16x32_bf16(A2, bv, acc[2][(nb_)], 0, 0, 0); \
    acc[3][(nb_)] = __builtin_amdgcn_mfma_f32_16x16x32_bf16(A3, bv, acc[3][(nb_)], 0, 0, 0); \
    __builtin_amdgcn_sched_group_barrier(0x020, 1, 0);                                 \
    __builtin_amdgcn_sched_group_barrier(0x008, 4, 0);                                 \
} while (0)

__global__ __launch_bounds__(256, 2) void k_conv(const u16* __restrict__ xt,
                                                 const u16* __restrict__ wt,
                                                 const float* __restrict__ scalar_bias,
                                                 const float* __restrict__ gate_bias,
                                                 u16* __restrict__ zt) {
    __shared__ __align__(16) u16 sx[12 * LP];
    const int bx = blockIdx.x;
    const int ht = bx & 3, d = (bx >> 2) & 31, b = bx >> 7;
    const int h0 = ht * 8;
    const int tid = threadIdx.x, lane = tid & 63, wv = tid >> 6;
    const int c15 = lane & 15, q16 = lane >> 4;

    floatx4 acc[4][11];
    #pragma unroll
    for (int i = 0; i < 4; ++i) {
        #pragma unroll
        for (int j = 0; j < 11; ++j) acc[i][j] = (floatx4){0.f, 0.f, 0.f, 0.f};
    }

    const int laneA = c15 * 72 + q16 * 8;

    for (int kd = 0; kd < 5; ++kd) {
        const int dp = d + kd - 2;
        if (dp < 0 || dp >= 32) continue;            // block-uniform
        // ---- stage one d-slice into LDS (zero-fill halos & k-pad region) ----
        const u16* srcbase = xt + (size_t)((b * 32 + dp) * 32) * 2304;
        for (int idx = tid; idx < 12 * 328; idx += 256) {
            int r = idx / 328, c = idx - r * 328;
            int hp = h0 + r - 2;
            uint4 val = make_uint4(0u, 0u, 0u, 0u);
            if (hp >= 0 && hp < 32 && c >= 18 && c < 306)
                val = *(const uint4*)(srcbase + (size_t)hp * 2304 + (c * 8 - 144));
            *(uint4*)(&sx[r * LP + c * 8]) = val;
        }
        __syncthreads();

        const u16* wt_kd = wt + (size_t)kd * 5 * 67584 + lane * 8;   // 12*11*512=67584
        for (int kh = 0; kh < 5; ++kh) {
            const u16* bq = wt_kd + (size_t)kh * 67584;
            const u16* sxrow = &sx[(2 * wv + kh) * LP + laneA];

            short8 q[2];
            q[0] = *(const short8*)(bq);
            q[1] = *(const short8*)(bq + 512);

            #pragma unroll
            for (int kb = 0; kb < 12; ++kb) {
                short8 A0 = *(const short8*)(sxrow + kb * 32);
                short8 A1 = *(const short8*)(sxrow + kb * 32 + 1152);
                short8 A2 = *(const short8*)(sxrow + kb * 32 + LP);
                short8 A3 = *(const short8*)(sxrow + kb * 32 + LP + 1152);
                __builtin_amdgcn_sched_group_barrier(0x100, 4, 0);
                GRP(kb, 0);  GRP(kb, 1);  GRP(kb, 2);  GRP(kb, 3);
                GRP(kb, 4);  GRP(kb, 5);  GRP(kb, 6);  GRP(kb, 7);
                GRP(kb, 8);  GRP(kb, 9);  GRP(kb, 10);
            }
        }
        __syncthreads();
    }

    // ---- epilogue: fused gate + bf16 store to zt ----
    // C/D layout: col(co) = lane&15, row(pos) = q16*4 + reg.
    const float sb = scalar_bias[c15];
    int   slA[9];
    float gbA[9];
    #pragma unroll
    for (int nb = 1; nb <= 8; ++nb) {
        int idx = (nb - 1) * 16 + c15;                       // co_f - 16
        int mul = (nb <= 3) ? (idx / 3) : (16 + (idx - 48) / 5);
        slA[nb] = (lane & 48) | (mul & 15);
        gbA[nb] = gate_bias[mul];
    }
    #pragma unroll
    for (int mi = 0; mi < 4; ++mi) {
        const int hl = 2 * wv + (mi >> 1);
        const int wh = mi & 1;
        const size_t zrow0 = (size_t)((b * 32 + d) * 32 + (h0 + hl)) * 32;
        #pragma unroll
        for (int r = 0; r < 4; ++r) {
            const int w = wh * 16 + q16 * 4 + r;
            u16* zp = zt + (zrow0 + w) * 144;
            zp[c15] = f2bf(fmaxf(acc[mi][0][r] + sb, 0.f));   // scalar field: relu+bias
            const float g9v  = acc[mi][9][r];
            const float g10v = acc[mi][10][r];
            #pragma unroll
            for (int nb = 1; nb <= 8; ++nb) {
                float ys = __shfl((nb <= 3) ? g9v : g10v, slA[nb], 64);
                float g  = 1.f / (1.f + __expf(-(ys + gbA[nb])));
                zp[nb * 16 + c15] = f2bf(acc[mi][nb][r] * g);
            }
        }
    }
}

// ---------------------------------------------------------------------------
// Low-pass, separable 3-pass (coalesced).  lw = Gaussian, sums to 1.
// P1 (w, stride 2): zt [b,d,h,w,144] -> t1 [b,d,h,ow16,144]
// P2 (h, stride 2): t1 -> t2 [b,d,oh16,ow16,144]
// P3 (d, stride 2): t2 -> out f32 NCDHW [4][144][16][16][16]
// ---------------------------------------------------------------------------
__constant__ float LW5[5] = {0.03208210f, 0.23705644f, 0.46172277f, 0.23705644f, 0.03208210f};

__global__ __launch_bounds__(256) void k_lp_w(const u16* __restrict__ zt,
                                              u16* __restrict__ t1) {
    __shared__ u16 row[4608];
    const int bx = blockIdx.x;               // (b*32+d)*32+h, 4096 blocks
    const int tid = threadIdx.x;
    const uint4* src = (const uint4*)(zt + (size_t)bx * 4608);
    for (int i = tid; i < 576; i += 256) ((uint4*)row)[i] = src[i];
    __syncthreads();
    u16* dst = t1 + (size_t)bx * 2304;
    for (int e = tid; e < 2304; e += 256) {
        const int ow = e / 144, c = e - ow * 144;
        const int wb = 2 * ow - 2;
        float a = 0.f;
        #pragma unroll
        for (int kw = 0; kw < 5; ++kw) {
            const int wz = wb + kw;
            if (wz >= 0 && wz < 32) a += LW5[kw] * bf2f(row[wz * 144 + c]);
        }
        dst[e] = f2bf(a);
    }
}

__global__ __launch_bounds__(256) void k_lp_h(const u16* __restrict__ t1,
                                              u16* __restrict__ t2) {
    const int gid = blockIdx.x * 256 + threadIdx.x;  // 2304 blocks -> 589824 = 128*16*16*18
    const int c8 = gid % 18;
    int t = gid / 18;
    const int ow = t & 15; t >>= 4;
    const int oh = t & 15; t >>= 4;                  // t = b*32+d  (0..127)
    const u16* base = t1 + (size_t)t * 32 * 2304 + ow * 144 + c8 * 8;
    float a[8];
    #pragma unroll
    for (int j = 0; j < 8; ++j) a[j] = 0.f;
    const int hb = 2 * oh - 2;
    #pragma unroll
    for (int kh = 0; kh < 5; ++kh) {
        const int hz = hb + kh;
        if (hz < 0 || hz >= 32) continue;
        u16 v[8] __attribute__((aligned(16)));
        *(uint4*)v = *(const uint4*)(base + (size_t)hz * 2304);
        const float wgt = LW5[kh];
        #pragma unroll
        for (int j = 0; j < 8; ++j) a[j] += wgt * bf2f(v[j]);
    }
    u16 o[8] __attribute__((aligned(16)));
    #pragma unroll
    for (int j = 0; j < 8; ++j) o[j] = f2bf(a[j]);
    *(uint4*)(t2 + ((size_t)(t * 16 + oh) * 16 + ow) * 144 + c8 * 8) = *(const uint4*)o;
}

__global__ __launch_bounds__(256) void k_lp_d(const u16* __restrict__ t2,
                                              float* __restrict__ out) {
    __shared__ u16 rows[5 * 2304];
    const int bx = blockIdx.x;               // (b*16+od)*16+oh, 1024 blocks
    const int tid = threadIdx.x;
    const int oh = bx & 15, od = (bx >> 4) & 15, b = bx >> 8;
    const int db = 2 * od - 2;
    for (int i = tid; i < 5 * 288; i += 256) {
        const int kd = i / 288, j = i - kd * 288;
        const int dz = db + kd;
        uint4 v = make_uint4(0u, 0u, 0u, 0u);
        if (dz >= 0 && dz < 32)
            v = ((const uint4*)(t2 + ((size_t)((b * 32 + dz) * 16 + oh) * 16) * 144))[j];
        ((uint4*)rows)[i] = v;
    }
    __syncthreads();
    for (int e = tid; e < 2304; e += 256) {
        const int c = e >> 4, ow = e & 15;
        float a = 0.f;
        #pragma unroll
        for (int kd = 0; kd < 5; ++kd)
            a += LW5[kd] * bf2f(rows[kd * 2304 + ow * 144 + c]);
        out[(((size_t)b * 144 + c) << 12) + (od << 8) + (oh << 4) + ow] = a;
    }
}

// ---------------------------------------------------------------------------
extern "C" void kernel_launch(void* const* d_in, const int* in_sizes, int n_in,
                              void* d_out, int out_size, void* d_ws, size_t ws_size,
                              hipStream_t stream) {
    const float* x  = (const float*)d_in[0];   // 4*72*32^3
    const float* W  = (const float*)d_in[1];   // 176*72*125
    const float* sb = (const float*)d_in[2];   // 16
    const float* gb = (const float*)d_in[3];   // 32
    float* out = (float*)d_out;                // 4*144*16^3 f32

    char* ws = (char*)d_ws;
    u16* xt = (u16*)(ws);                      // 18,874,368 B  (dead after k_conv)
    u16* wt = (u16*)(ws + 18874368);           //  3,379,200 B
    u16* zt = (u16*)(ws + 22253568);           // 37,748,736 B  (dead after k_lp_w)
    u16* t1 = xt;                              // 18,874,368 B  (exact size match)
    u16* t2 = zt;                              //  9,437,184 B

    hipLaunchKernelGGL(k_transpose_x, dim3(4096), dim3(256), 0, stream, x, xt);
    hipLaunchKernelGGL(k_prep_w,      dim3(825),  dim3(256), 0, stream, W, wt);
    hipLaunchKernelGGL(k_conv,        dim3(512),  dim3(256), 0, stream, xt, wt, sb, gb, zt);
    hipLaunchKernelGGL(k_lp_w,        dim3(4096), dim3(256), 0, stream, zt, t1);
    hipLaunchKernelGGL(k_lp_h,        dim3(2304), dim3(256), 0, stream, t1, t2);
    hipLaunchKernelGGL(k_lp_d,        dim3(1024), dim3(256), 0, stream, t2, out);
}

// Round 4
// 918.983 us; speedup vs baseline: 1.1209x; 1.1209x over previous
//
#include <hip/hip_runtime.h>
#include <cstdint>
#include <cstddef>

typedef short short8 __attribute__((ext_vector_type(8)));
typedef float floatx4 __attribute__((ext_vector_type(4)));
typedef unsigned short u16;

__device__ __forceinline__ u16 f2bf(float f) {
    unsigned u = __float_as_uint(f);
    u += 0x7FFFu + ((u >> 16) & 1u);
    return (u16)(u >> 16);
}
__device__ __forceinline__ float bf2f(u16 h) {
    return __uint_as_float(((unsigned)h) << 16);
}

// ---------------------------------------------------------------------------
// Kernel 1: x [4][72][32][32][32] f32 (NCDHW)  ->  xt [4][32][32][32][72] bf16
// ---------------------------------------------------------------------------
__global__ __launch_bounds__(256) void k_transpose_x(const float* __restrict__ x,
                                                     u16* __restrict__ xt) {
    __shared__ float tile[72 * 33];
    const int bx = blockIdx.x;               // ((b*32+d)*32+h)
    const int tid = threadIdx.x;
    const int b = bx >> 10, d = (bx >> 5) & 31, h = bx & 31;
    const float* src = x + (size_t)b * 72 * 32768 + d * 1024 + h * 32;
    for (int e = tid; e < 2304; e += 256) {
        int ci = e >> 5, w = e & 31;
        tile[ci * 33 + w] = src[(size_t)ci * 32768 + w];
    }
    __syncthreads();
    u16* dst = xt + (size_t)bx * 2304;
    for (int e = tid; e < 2304; e += 256) {
        int w = e / 72, ci = e - w * 72;
        dst[e] = f2bf(tile[ci * 33 + w]);
    }
}

// ---------------------------------------------------------------------------
// Kernel 2: W [176][72][5][5][5] f32 -> wt bf16 per-lane B-fragment layout:
//   wt[kd][kh][kblk(12)][nblk(11)][lane(64)][8]
// ---------------------------------------------------------------------------
__global__ __launch_bounds__(256) void k_prep_w(const float* __restrict__ W,
                                                u16* __restrict__ wt) {
    const int gid = blockIdx.x * 256 + threadIdx.x;   // 825*256 = 211200 = 3300 frags * 64
    const int frag = gid >> 6, lane = gid & 63;
    const int nb = frag % 11;
    int t = frag / 11;
    const int kb = t % 12;
    t = t / 12;
    const int kh = t % 5, kd = t / 5;
    const int n = lane & 15, q8 = (lane >> 4) * 8;
    const int co = nb * 16 + n;
    u16 v[8] __attribute__((aligned(16)));
    #pragma unroll
    for (int j = 0; j < 8; ++j) {
        int k = kb * 32 + q8 + j;
        u16 r = 0;
        if (k < 360) {
            int kw = k / 72, ci = k - kw * 72;
            r = f2bf(W[((size_t)co * 72 + ci) * 125 + kd * 25 + kh * 5 + kw]);
        }
        v[j] = r;
    }
    *(uint4*)(wt + (size_t)gid * 8) = *(const uint4*)v;
}

// ---------------------------------------------------------------------------
// Kernel 3: implicit-GEMM conv + fused gating.
// WG tile: M=256 pos (8h x 32w), N=176. Waves = {M-half: 8 blocks} x {N-half}.
// mA=8 halves B-bytes/MFMA vs R1 (L1-return-path was the binding pipe).
// Gate channels (nb 9,10) exchanged across waves via LDS (reuses sx).
// ---------------------------------------------------------------------------
#define LP 2624

template<int NBC, int NST>
__device__ __forceinline__ void conv_main(
    const u16* __restrict__ xt, const u16* __restrict__ wt,
    const float* __restrict__ scalar_bias, const float* __restrict__ gate_bias,
    u16* __restrict__ zt, u16* sx,
    int b, int d, int h0, int tid, int mb0, int nb0)
{
    const int lane = tid & 63;
    const int c15 = lane & 15, q16 = lane >> 4;
    const int laneA = c15 * 72 + q16 * 8;

    floatx4 acc[8][6];
    #pragma unroll
    for (int i = 0; i < 8; ++i)
        #pragma unroll
        for (int j = 0; j < 6; ++j) acc[i][j] = (floatx4){0.f, 0.f, 0.f, 0.f};

    for (int kd = 0; kd < 5; ++kd) {
        const int dp = d + kd - 2;
        if (dp < 0 || dp >= 32) continue;            // WG-uniform
        // ---- stage d-slice into LDS (zero halos & K-pad) ----
        const u16* srcbase = xt + (size_t)((b * 32 + dp) * 32) * 2304;
        for (int idx = tid; idx < 12 * 328; idx += 256) {
            int r = idx / 328, c = idx - r * 328;
            int hp = h0 + r - 2;
            uint4 val = make_uint4(0u, 0u, 0u, 0u);
            if (hp >= 0 && hp < 32 && c >= 18 && c < 306)
                val = *(const uint4*)(srcbase + (size_t)hp * 2304 + (c * 8 - 144));
            *(uint4*)(&sx[r * LP + c * 8]) = val;
        }
        __syncthreads();

        const u16* wt_kd = wt + (size_t)kd * 337920 + lane * 8 + nb0 * 512;
        for (int kh = 0; kh < 5; ++kh) {
            const u16* bq = wt_kd + (size_t)kh * 67584;
            const u16* arow = &sx[kh * LP + laneA];
            #pragma unroll 4
            for (int kb = 0; kb < 12; ++kb) {
                short8 B[NBC];
                #pragma unroll
                for (int j = 0; j < NBC; ++j)
                    B[j] = *(const short8*)(bq + (size_t)(kb * 11 + j) * 512);
                #pragma unroll
                for (int half = 0; half < 2; ++half) {
                    short8 A[4];
                    #pragma unroll
                    for (int i = 0; i < 4; ++i) {
                        const int mi = half * 4 + i;
                        const int hl = (mb0 + mi) >> 1, wh = (mb0 + mi) & 1;
                        A[i] = *(const short8*)(arow + hl * LP + wh * 1152 + kb * 32);
                    }
                    #pragma unroll
                    for (int i = 0; i < 4; ++i)
                        #pragma unroll
                        for (int j = 0; j < NBC; ++j)
                            acc[half * 4 + i][j] = __builtin_amdgcn_mfma_f32_16x16x32_bf16(
                                A[i], B[j], acc[half * 4 + i][j], 0, 0, 0);
                }
            }
        }
        __syncthreads();
    }

    // ---- epilogue ----
    float* gl = (float*)sx;   // gates[pos 256][mul 32] f32 = 32 KB (sx is dead)
    if (NBC == 5) {           // this wave owns nb 9 (local 3) and nb 10 (local 4)
        const float gb9  = gate_bias[c15];
        const float gb10 = gate_bias[16 + c15];
        #pragma unroll
        for (int mi = 0; mi < 8; ++mi) {
            const int hl = (mb0 + mi) >> 1, wh = (mb0 + mi) & 1;
            #pragma unroll
            for (int r = 0; r < 4; ++r) {
                const int pos = hl * 32 + wh * 16 + q16 * 4 + r;
                gl[pos * 32 + c15]      = 1.f / (1.f + __expf(-(acc[mi][3][r] + gb9)));
                gl[pos * 32 + 16 + c15] = 1.f / (1.f + __expf(-(acc[mi][4][r] + gb10)));
            }
        }
    }
    __syncthreads();

    const float sbv = (nb0 == 0) ? scalar_bias[c15] : 0.f;
    int mulj[NST];
    #pragma unroll
    for (int j = 0; j < NST; ++j) {
        const int nb = nb0 + j;
        const int co = nb * 16 + c15;
        mulj[j] = (nb == 0) ? 0 : ((co < 64) ? (co - 16) / 3 : 16 + (co - 64) / 5);
    }
    #pragma unroll
    for (int mi = 0; mi < 8; ++mi) {
        const int hl = (mb0 + mi) >> 1, wh = (mb0 + mi) & 1;
        const size_t zrow = (size_t)((b * 32 + d) * 32 + h0 + hl) * 32;
        #pragma unroll
        for (int r = 0; r < 4; ++r) {
            const int w = wh * 16 + q16 * 4 + r;
            const int pos = hl * 32 + w;
            u16* zp = zt + (zrow + w) * 144;
            #pragma unroll
            for (int j = 0; j < NST; ++j) {
                const int nb = nb0 + j;
                const float v = acc[mi][j][r];
                if (nb == 0) {
                    zp[c15] = f2bf(fmaxf(v + sbv, 0.f));
                } else {
                    const float g = gl[pos * 32 + mulj[j]];
                    zp[nb * 16 + c15] = f2bf(v * g);
                }
            }
        }
    }
}

__global__ __launch_bounds__(256, 2) void k_conv(const u16* __restrict__ xt,
                                                 const u16* __restrict__ wt,
                                                 const float* __restrict__ scalar_bias,
                                                 const float* __restrict__ gate_bias,
                                                 u16* __restrict__ zt) {
    __shared__ __align__(16) u16 sx[12 * LP];
    const int bx = blockIdx.x;
    const int ht = bx & 3, d = (bx >> 2) & 31, b = bx >> 7;
    const int h0 = ht * 8;
    const int tid = threadIdx.x;
    // role swizzle by block parity so heavy (6-nb) waves spread across SIMDs
    const int role = ((tid >> 6) + 2 * (bx & 1)) & 3;
    const int mb0 = (role & 1) * 8;
    if (role < 2)
        conv_main<6, 6>(xt, wt, scalar_bias, gate_bias, zt, sx, b, d, h0, tid, mb0, 0);
    else
        conv_main<5, 3>(xt, wt, scalar_bias, gate_bias, zt, sx, b, d, h0, tid, mb0, 6);
}

// ---------------------------------------------------------------------------
// Low-pass, separable 3-pass (coalesced).
// ---------------------------------------------------------------------------
__constant__ float LW5[5] = {0.03208210f, 0.23705644f, 0.46172277f, 0.23705644f, 0.03208210f};

__global__ __launch_bounds__(256) void k_lp_w(const u16* __restrict__ zt,
                                              u16* __restrict__ t1) {
    __shared__ u16 row[4608];
    const int bx = blockIdx.x;               // (b*32+d)*32+h, 4096 blocks
    const int tid = threadIdx.x;
    const uint4* src = (const uint4*)(zt + (size_t)bx * 4608);
    for (int i = tid; i < 576; i += 256) ((uint4*)row)[i] = src[i];
    __syncthreads();
    u16* dst = t1 + (size_t)bx * 2304;
    for (int e = tid; e < 2304; e += 256) {
        const int ow = e / 144, c = e - ow * 144;
        const int wb = 2 * ow - 2;
        float a = 0.f;
        #pragma unroll
        for (int kw = 0; kw < 5; ++kw) {
            const int wz = wb + kw;
            if (wz >= 0 && wz < 32) a += LW5[kw] * bf2f(row[wz * 144 + c]);
        }
        dst[e] = f2bf(a);
    }
}

__global__ __launch_bounds__(256) void k_lp_h(const u16* __restrict__ t1,
                                              u16* __restrict__ t2) {
    const int gid = blockIdx.x * 256 + threadIdx.x;  // 2304 blocks -> 589824 = 128*16*16*18
    const int c8 = gid % 18;
    int t = gid / 18;
    const int ow = t & 15; t >>= 4;
    const int oh = t & 15; t >>= 4;                  // t = b*32+d  (0..127)
    const u16* base = t1 + (size_t)t * 32 * 2304 + ow * 144 + c8 * 8;
    float a[8];
    #pragma unroll
    for (int j = 0; j < 8; ++j) a[j] = 0.f;
    const int hb = 2 * oh - 2;
    #pragma unroll
    for (int kh = 0; kh < 5; ++kh) {
        const int hz = hb + kh;
        if (hz < 0 || hz >= 32) continue;
        u16 v[8] __attribute__((aligned(16)));
        *(uint4*)v = *(const uint4*)(base + (size_t)hz * 2304);
        const float wgt = LW5[kh];
        #pragma unroll
        for (int j = 0; j < 8; ++j) a[j] += wgt * bf2f(v[j]);
    }
    u16 o[8] __attribute__((aligned(16)));
    #pragma unroll
    for (int j = 0; j < 8; ++j) o[j] = f2bf(a[j]);
    *(uint4*)(t2 + ((size_t)(t * 16 + oh) * 16 + ow) * 144 + c8 * 8) = *(const uint4*)o;
}

__global__ __launch_bounds__(256) void k_lp_d(const u16* __restrict__ t2,
                                              float* __restrict__ out) {
    __shared__ u16 rows[5 * 2304];
    const int bx = blockIdx.x;               // (b*16+od)*16+oh, 1024 blocks
    const int tid = threadIdx.x;
    const int oh = bx & 15, od = (bx >> 4) & 15, b = bx >> 8;
    const int db = 2 * od - 2;
    for (int i = tid; i < 5 * 288; i += 256) {
        const int kd = i / 288, j = i - kd * 288;
        const int dz = db + kd;
        uint4 v = make_uint4(0u, 0u, 0u, 0u);
        if (dz >= 0 && dz < 32)
            v = ((const uint4*)(t2 + ((size_t)((b * 32 + dz) * 16 + oh) * 16) * 144))[j];
        ((uint4*)rows)[i] = v;
    }
    __syncthreads();
    for (int e = tid; e < 2304; e += 256) {
        const int c = e >> 4, ow = e & 15;
        float a = 0.f;
        #pragma unroll
        for (int kd = 0; kd < 5; ++kd)
            a += LW5[kd] * bf2f(rows[kd * 2304 + ow * 144 + c]);
        out[(((size_t)b * 144 + c) << 12) + (od << 8) + (oh << 4) + ow] = a;
    }
}

// ---------------------------------------------------------------------------
extern "C" void kernel_launch(void* const* d_in, const int* in_sizes, int n_in,
                              void* d_out, int out_size, void* d_ws, size_t ws_size,
                              hipStream_t stream) {
    const float* x  = (const float*)d_in[0];   // 4*72*32^3
    const float* W  = (const float*)d_in[1];   // 176*72*125
    const float* sb = (const float*)d_in[2];   // 16
    const float* gb = (const float*)d_in[3];   // 32
    float* out = (float*)d_out;                // 4*144*16^3 f32

    char* ws = (char*)d_ws;
    u16* xt = (u16*)(ws);                      // 18,874,368 B  (dead after k_conv)
    u16* wt = (u16*)(ws + 18874368);           //  3,379,200 B
    u16* zt = (u16*)(ws + 22253568);           // 37,748,736 B  (dead after k_lp_w)
    u16* t1 = xt;                              // reuse
    u16* t2 = zt;                              // reuse

    hipLaunchKernelGGL(k_transpose_x, dim3(4096), dim3(256), 0, stream, x, xt);
    hipLaunchKernelGGL(k_prep_w,      dim3(825),  dim3(256), 0, stream, W, wt);
    hipLaunchKernelGGL(k_conv,        dim3(512),  dim3(256), 0, stream, xt, wt, sb, gb, zt);
    hipLaunchKernelGGL(k_lp_w,        dim3(4096), dim3(256), 0, stream, zt, t1);
    hipLaunchKernelGGL(k_lp_h,        dim3(2304), dim3(256), 0, stream, t1, t2);
    hipLaunchKernelGGL(k_lp_d,        dim3(1024), dim3(256), 0, stream, t2, out);
}